// Round 1
// baseline (1258.091 us; speedup 1.0000x reference)
//
#include <hip/hip_runtime.h>

#define BATCH 64
#define NIN 1024
#define IVL 64
#define ONUM 64
#define LVL 32
#define OLSZ 2048  // ONUM*LVL

typedef __attribute__((ext_vector_type(4))) float f32x4;
typedef __attribute__((ext_vector_type(8))) short short8;

static __device__ __forceinline__ unsigned short f2bf(float f) {
  unsigned u = __builtin_bit_cast(unsigned, f);
  u += 0x7fffu + ((u >> 16) & 1u);
  return (unsigned short)(u >> 16);
}
static __device__ __forceinline__ float bf2f(unsigned short h) {
  unsigned u = ((unsigned)h) << 16;
  return __builtin_bit_cast(float, u);
}

// K1: u_hat[b,n,o,l] = sum_i u[b,n,i]*W[n,o,l,i] + bias[n,o,l], stored bf16.
// One workgroup per n. A = u[:,n,:] (64x64) in LDS (bf16, padded stride 72).
// W streamed global->reg, converted to bf16 in flight.
__global__ __launch_bounds__(256) void k_gemm(
    const float* __restrict__ u, const float* __restrict__ w,
    const float* __restrict__ bias, unsigned short* __restrict__ uhat) {
  const int n = blockIdx.x;
  __shared__ __align__(16) unsigned short a_lds[64 * 72];
  const int t = threadIdx.x;
  {
    const int b = t >> 2;
    const int i0 = (t & 3) * 16;
    const float* src = u + (size_t)b * (NIN * IVL) + (size_t)n * IVL + i0;
    unsigned short* dst = a_lds + b * 72 + i0;
#pragma unroll
    for (int q = 0; q < 4; ++q) {
      float4 v = *(const float4*)(src + q * 4);
      dst[q * 4 + 0] = f2bf(v.x);
      dst[q * 4 + 1] = f2bf(v.y);
      dst[q * 4 + 2] = f2bf(v.z);
      dst[q * 4 + 3] = f2bf(v.w);
    }
  }
  __syncthreads();
  const int lane = t & 63;
  const int wave = t >> 6;
  const int row16 = lane & 15;
  const int quad = lane >> 4;

  // A fragments: 4 b-tiles x 2 k-steps. lane: row = lane%16, k = 8*(lane/16)+j
  short8 afrag[4][2];
#pragma unroll
  for (int bt = 0; bt < 4; ++bt) {
#pragma unroll
    for (int ks = 0; ks < 2; ++ks) {
      afrag[bt][ks] =
          *(const short8*)(a_lds + (bt * 16 + row16) * 72 + ks * 32 + quad * 8);
    }
  }

  const float* wbase = w + (size_t)n * (OLSZ * IVL);
  const float* bbase = bias + (size_t)n * OLSZ;

  for (int olt = wave * 32; olt < wave * 32 + 32; ++olt) {
    const int col = olt * 16 + row16;
    const float* wp = wbase + (size_t)col * IVL + quad * 8;
    float4 wa = *(const float4*)(wp);
    float4 wb = *(const float4*)(wp + 4);
    float4 wc = *(const float4*)(wp + 32);
    float4 wd = *(const float4*)(wp + 36);
    short8 bf0, bf1;
    bf0[0] = (short)f2bf(wa.x); bf0[1] = (short)f2bf(wa.y);
    bf0[2] = (short)f2bf(wa.z); bf0[3] = (short)f2bf(wa.w);
    bf0[4] = (short)f2bf(wb.x); bf0[5] = (short)f2bf(wb.y);
    bf0[6] = (short)f2bf(wb.z); bf0[7] = (short)f2bf(wb.w);
    bf1[0] = (short)f2bf(wc.x); bf1[1] = (short)f2bf(wc.y);
    bf1[2] = (short)f2bf(wc.z); bf1[3] = (short)f2bf(wc.w);
    bf1[4] = (short)f2bf(wd.x); bf1[5] = (short)f2bf(wd.y);
    bf1[6] = (short)f2bf(wd.z); bf1[7] = (short)f2bf(wd.w);

    f32x4 acc[4];
#pragma unroll
    for (int bt = 0; bt < 4; ++bt) acc[bt] = (f32x4){0.f, 0.f, 0.f, 0.f};
#pragma unroll
    for (int bt = 0; bt < 4; ++bt) {
      acc[bt] = __builtin_amdgcn_mfma_f32_16x16x32_bf16(afrag[bt][0], bf0,
                                                        acc[bt], 0, 0, 0);
      acc[bt] = __builtin_amdgcn_mfma_f32_16x16x32_bf16(afrag[bt][1], bf1,
                                                        acc[bt], 0, 0, 0);
    }
    const float bv = bbase[col];
#pragma unroll
    for (int bt = 0; bt < 4; ++bt) {
#pragma unroll
      for (int r = 0; r < 4; ++r) {
        const int brow = bt * 16 + quad * 4 + r;
        uhat[((size_t)brow * NIN + n) * OLSZ + col] = f2bf(acc[bt][r] + bv);
      }
    }
  }
}

// K2: s1[b,o,l] = sum_n uhat[b,n,o,l]  (atomic fp32 partials over 4 n-chunks)
__global__ __launch_bounds__(256) void k_sum_n(
    const unsigned short* __restrict__ uhat, float* __restrict__ s1) {
  const int bx = blockIdx.x;  // 512 blocks: b(64) x olh(2) x nc(4)
  const int b = bx >> 3;
  const int olh = (bx >> 2) & 1;
  const int nc = bx & 3;
  const int t = threadIdx.x;
  const int ol0 = olh * 1024 + t * 4;
  float a0 = 0.f, a1 = 0.f, a2 = 0.f, a3 = 0.f;
  const unsigned short* base =
      uhat + ((size_t)b * NIN + (size_t)nc * 256) * OLSZ + ol0;
#pragma unroll 8
  for (int k = 0; k < 256; ++k) {
    ushort4 v = *(const ushort4*)(base + (size_t)k * OLSZ);
    a0 += bf2f(v.x); a1 += bf2f(v.y); a2 += bf2f(v.z); a3 += bf2f(v.w);
  }
  float* s = s1 + b * OLSZ + ol0;
  atomicAdd(s + 0, a0); atomicAdd(s + 1, a1);
  atomicAdd(s + 2, a2); atomicAdd(s + 3, a3);
}

// K3/K4: one routing iteration.
//  v = squash(sv * scale) computed into LDS per block.
//  per n: d = sum_l ud*v ; bno = d (+ b1 if add_b1) ; c = softmax_o(bno)
//  accumulate sout[b,o,l] += c*ud  (register partials -> atomicAdd)
__global__ __launch_bounds__(256) void k_route(
    const unsigned short* __restrict__ uhat, const float* __restrict__ sv,
    float scale, float* __restrict__ b1, int add_b1,
    float* __restrict__ sout) {
  const int b = blockIdx.x >> 4;
  const int chunk = blockIdx.x & 15;
  const int t = threadIdx.x;
  __shared__ float v_lds[64 * 33];
  __shared__ float norm2[64];
  if (t < 64) norm2[t] = 0.f;
  __syncthreads();
  float scv[8];
#pragma unroll
  for (int k = 0; k < 8; ++k) {
    int idx = t + k * 256;
    float sc = sv[b * OLSZ + idx] * scale;
    scv[k] = sc;
    atomicAdd(&norm2[idx >> 5], sc * sc);
  }
  __syncthreads();
#pragma unroll
  for (int k = 0; k < 8; ++k) {
    int idx = t + k * 256;
    int o = idx >> 5;
    float n2 = norm2[o];
    float f = n2 / ((1.f + n2) * (sqrtf(n2) + 1e-5f));
    v_lds[o * 33 + (idx & 31)] = scv[k] * f;
  }
  __syncthreads();

  const int lane = t & 63;  // lane = o
  const int wave = t >> 6;
  float racc[32];
#pragma unroll
  for (int j = 0; j < 32; ++j) racc[j] = 0.f;
  const int nbase = chunk * 64 + wave * 16;
  for (int k = 0; k < 16; ++k) {
    const int n = nbase + k;
    const unsigned short* up =
        uhat + ((size_t)b * NIN + n) * OLSZ + lane * LVL;
    float ud[32];
#pragma unroll
    for (int q = 0; q < 4; ++q) {
      uint4 qq = *(const uint4*)(up + q * 8);
      unsigned xs[4] = {qq.x, qq.y, qq.z, qq.w};
#pragma unroll
      for (int h = 0; h < 4; ++h) {
        ud[q * 8 + h * 2] = __builtin_bit_cast(float, xs[h] << 16);
        ud[q * 8 + h * 2 + 1] = __builtin_bit_cast(float, xs[h] & 0xffff0000u);
      }
    }
    float d = 0.f;
#pragma unroll
    for (int j = 0; j < 32; ++j) d = fmaf(ud[j], v_lds[lane * 33 + j], d);
    float bno = d;
    const size_t bidx = ((size_t)b * NIN + n) * ONUM + lane;
    if (add_b1) bno += b1[bidx];
    else        b1[bidx] = bno;
    float m = bno;
#pragma unroll
    for (int dlt = 1; dlt < 64; dlt <<= 1) m = fmaxf(m, __shfl_xor(m, dlt));
    float e = __expf(bno - m);
    float ssum = e;
#pragma unroll
    for (int dlt = 1; dlt < 64; dlt <<= 1) ssum += __shfl_xor(ssum, dlt);
    float c = e / ssum;
#pragma unroll
    for (int j = 0; j < 32; ++j) racc[j] = fmaf(c, ud[j], racc[j]);
  }
  float* so = sout + b * OLSZ + lane * LVL;
#pragma unroll
  for (int j = 0; j < 32; ++j) atomicAdd(so + j, racc[j]);
}

// K5: out = squash(s3)
__global__ __launch_bounds__(256) void k_final(const float* __restrict__ s3,
                                               float* __restrict__ out) {
  const int b = blockIdx.x;
  const int t = threadIdx.x;
  __shared__ float norm2[64];
  if (t < 64) norm2[t] = 0.f;
  __syncthreads();
  float scv[8];
#pragma unroll
  for (int k = 0; k < 8; ++k) {
    int idx = t + k * 256;
    float sc = s3[b * OLSZ + idx];
    scv[k] = sc;
    atomicAdd(&norm2[idx >> 5], sc * sc);
  }
  __syncthreads();
#pragma unroll
  for (int k = 0; k < 8; ++k) {
    int idx = t + k * 256;
    int o = idx >> 5;
    float n2 = norm2[o];
    float f = n2 / ((1.f + n2) * (sqrtf(n2) + 1e-5f));
    out[b * OLSZ + idx] = scv[k] * f;
  }
}

extern "C" void kernel_launch(void* const* d_in, const int* in_sizes, int n_in,
                              void* d_out, int out_size, void* d_ws,
                              size_t ws_size, hipStream_t stream) {
  const float* u = (const float*)d_in[0];
  const float* w = (const float*)d_in[1];
  const float* bias = (const float*)d_in[2];
  float* out = (float*)d_out;

  char* ws = (char*)d_ws;
  unsigned short* uhat = (unsigned short*)ws;                 // 268435456 B
  float* b1 = (float*)(ws + (size_t)268435456);               // 16777216 B
  float* s1 = (float*)(ws + (size_t)268435456 + 16777216);    // 524288 B
  float* s2 = s1 + 131072;                                    // 524288 B
  float* s3 = s2 + 131072;                                    // 524288 B

  hipMemsetAsync(s1, 0, 3 * 131072 * sizeof(float), stream);

  k_gemm<<<dim3(1024), dim3(256), 0, stream>>>(u, w, bias, uhat);
  k_sum_n<<<dim3(512), dim3(256), 0, stream>>>(uhat, s1);
  k_route<<<dim3(1024), dim3(256), 0, stream>>>(uhat, s1, 1.0f / 64.0f, b1, 0, s2);
  k_route<<<dim3(1024), dim3(256), 0, stream>>>(uhat, s2, 1.0f, b1, 1, s3);
  k_final<<<dim3(64), dim3(256), 0, stream>>>(s3, out);
}

// Round 2
// 599.533 us; speedup vs baseline: 2.0985x; 2.0985x over previous
//
#include <hip/hip_runtime.h>

#define BATCH 64
#define NIN 1024
#define IVL 64
#define ONUM 64
#define LVL 32
#define OLSZ 2048  // ONUM*LVL

typedef __attribute__((ext_vector_type(4))) float f32x4;
typedef __attribute__((ext_vector_type(8))) short short8;

static __device__ __forceinline__ unsigned short f2bf(float f) {
  unsigned u = __builtin_bit_cast(unsigned, f);
  u += 0x7fffu + ((u >> 16) & 1u);
  return (unsigned short)(u >> 16);
}
static __device__ __forceinline__ float bf2f_lo(unsigned x) {
  return __builtin_bit_cast(float, x << 16);
}
static __device__ __forceinline__ float bf2f_hi(unsigned x) {
  return __builtin_bit_cast(float, x & 0xffff0000u);
}

// K1: u_hat[b,n,o,l] = sum_i u[b,n,i]*W[n,o,l,i] + bias[n,o,l], stored bf16.
__global__ __launch_bounds__(256) void k_gemm(
    const float* __restrict__ u, const float* __restrict__ w,
    const float* __restrict__ bias, unsigned short* __restrict__ uhat) {
  const int n = blockIdx.x;
  __shared__ __align__(16) unsigned short a_lds[64 * 72];
  const int t = threadIdx.x;
  {
    const int b = t >> 2;
    const int i0 = (t & 3) * 16;
    const float* src = u + (size_t)b * (NIN * IVL) + (size_t)n * IVL + i0;
    unsigned short* dst = a_lds + b * 72 + i0;
#pragma unroll
    for (int q = 0; q < 4; ++q) {
      float4 v = *(const float4*)(src + q * 4);
      dst[q * 4 + 0] = f2bf(v.x);
      dst[q * 4 + 1] = f2bf(v.y);
      dst[q * 4 + 2] = f2bf(v.z);
      dst[q * 4 + 3] = f2bf(v.w);
    }
  }
  __syncthreads();
  const int lane = t & 63;
  const int wave = t >> 6;
  const int row16 = lane & 15;
  const int quad = lane >> 4;

  short8 afrag[4][2];
#pragma unroll
  for (int bt = 0; bt < 4; ++bt) {
#pragma unroll
    for (int ks = 0; ks < 2; ++ks) {
      afrag[bt][ks] =
          *(const short8*)(a_lds + (bt * 16 + row16) * 72 + ks * 32 + quad * 8);
    }
  }

  const float* wbase = w + (size_t)n * (OLSZ * IVL);
  const float* bbase = bias + (size_t)n * OLSZ;

  for (int olt = wave * 32; olt < wave * 32 + 32; ++olt) {
    const int col = olt * 16 + row16;
    const float* wp = wbase + (size_t)col * IVL + quad * 8;
    float4 wa = *(const float4*)(wp);
    float4 wb = *(const float4*)(wp + 4);
    float4 wc = *(const float4*)(wp + 32);
    float4 wd = *(const float4*)(wp + 36);
    short8 bf0, bf1;
    bf0[0] = (short)f2bf(wa.x); bf0[1] = (short)f2bf(wa.y);
    bf0[2] = (short)f2bf(wa.z); bf0[3] = (short)f2bf(wa.w);
    bf0[4] = (short)f2bf(wb.x); bf0[5] = (short)f2bf(wb.y);
    bf0[6] = (short)f2bf(wb.z); bf0[7] = (short)f2bf(wb.w);
    bf1[0] = (short)f2bf(wc.x); bf1[1] = (short)f2bf(wc.y);
    bf1[2] = (short)f2bf(wc.z); bf1[3] = (short)f2bf(wc.w);
    bf1[4] = (short)f2bf(wd.x); bf1[5] = (short)f2bf(wd.y);
    bf1[6] = (short)f2bf(wd.z); bf1[7] = (short)f2bf(wd.w);

    f32x4 acc[4];
#pragma unroll
    for (int bt = 0; bt < 4; ++bt) acc[bt] = (f32x4){0.f, 0.f, 0.f, 0.f};
#pragma unroll
    for (int bt = 0; bt < 4; ++bt) {
      acc[bt] = __builtin_amdgcn_mfma_f32_16x16x32_bf16(afrag[bt][0], bf0,
                                                        acc[bt], 0, 0, 0);
      acc[bt] = __builtin_amdgcn_mfma_f32_16x16x32_bf16(afrag[bt][1], bf1,
                                                        acc[bt], 0, 0, 0);
    }
    const float bv = bbase[col];
#pragma unroll
    for (int bt = 0; bt < 4; ++bt) {
#pragma unroll
      for (int r = 0; r < 4; ++r) {
        const int brow = bt * 16 + quad * 4 + r;
        uhat[((size_t)brow * NIN + n) * OLSZ + col] = f2bf(acc[bt][r] + bv);
      }
    }
  }
}

// K2: s1[b,ol] = sum_n uhat[b,n,ol]. Dense coalesced: thread t owns ol slice
// [t*8, t*8+8); block covers one b, 32 consecutive n.
__global__ __launch_bounds__(256) void k_sum_n(
    const unsigned short* __restrict__ uhat, float* __restrict__ s1) {
  const int b = blockIdx.x >> 5;
  const int chunk = blockIdx.x & 31;
  const int t = threadIdx.x;
  const unsigned short* base =
      uhat + ((size_t)b * NIN + (size_t)chunk * 32) * OLSZ + t * 8;
  float acc[8];
#pragma unroll
  for (int j = 0; j < 8; ++j) acc[j] = 0.f;
#pragma unroll 4
  for (int k = 0; k < 32; ++k) {
    uint4 p = *(const uint4*)(base + (size_t)k * OLSZ);
    unsigned xs[4] = {p.x, p.y, p.z, p.w};
#pragma unroll
    for (int h = 0; h < 4; ++h) {
      acc[2 * h] += bf2f_lo(xs[h]);
      acc[2 * h + 1] += bf2f_hi(xs[h]);
    }
  }
  float* s = s1 + (size_t)b * OLSZ + t * 8;
#pragma unroll
  for (int j = 0; j < 8; ++j) atomicAdd(s + j, acc[j]);
}

// K3/K4: one routing iteration, dense-coalesced + software pipelined.
// Element f = q*512 + lane*8 + j  <->  o = 16q + lane/4, l = (lane%4)*8 + j.
__global__ __launch_bounds__(256) void k_route(
    const unsigned short* __restrict__ uhat, const float* __restrict__ sv,
    float scale, float* __restrict__ b1, int add_b1,
    float* __restrict__ sout) {
  const int b = blockIdx.x >> 5;
  const int chunk = blockIdx.x & 31;
  const int t = threadIdx.x;
  const int lane = t & 63;
  const int wave = t >> 6;
  const int g = lane >> 2;
  __shared__ float red[4][OLSZ];  // 32 KB

  // v = squash(sv*scale), held in registers with the same dense mapping.
  float v[4][8];
#pragma unroll
  for (int q = 0; q < 4; ++q) {
    const float* svp = sv + (size_t)b * OLSZ + q * 512 + lane * 8;
    float4 a0 = *(const float4*)svp;
    float4 a1 = *(const float4*)(svp + 4);
    v[q][0] = a0.x * scale; v[q][1] = a0.y * scale;
    v[q][2] = a0.z * scale; v[q][3] = a0.w * scale;
    v[q][4] = a1.x * scale; v[q][5] = a1.y * scale;
    v[q][6] = a1.z * scale; v[q][7] = a1.w * scale;
    float p = 0.f;
#pragma unroll
    for (int j = 0; j < 8; ++j) p = fmaf(v[q][j], v[q][j], p);
    p += __shfl_xor(p, 1);
    p += __shfl_xor(p, 2);
    float f = p / ((1.f + p) * (sqrtf(p) + 1e-5f));
#pragma unroll
    for (int j = 0; j < 8; ++j) v[q][j] *= f;
  }

  float racc[4][8];
#pragma unroll
  for (int q = 0; q < 4; ++q)
#pragma unroll
    for (int j = 0; j < 8; ++j) racc[q][j] = 0.f;

  const int n0 = chunk * 32 + wave * 8;
  const unsigned short* ub = uhat + ((size_t)b * NIN + n0) * OLSZ + lane * 8;

  uint4 pA[4], pB[4];
#pragma unroll
  for (int q = 0; q < 4; ++q) pA[q] = *(const uint4*)(ub + q * 512);

  auto process = [&](const uint4(&pk)[4], int k) {
    const int n = n0 + k;
    const size_t bbase = ((size_t)b * NIN + n) * ONUM + g;
    float b1v[4];
    if (add_b1) {
#pragma unroll
      for (int q = 0; q < 4; ++q) b1v[q] = b1[bbase + 16 * q];
    }
    float ud[4][8];
    float d[4];
#pragma unroll
    for (int q = 0; q < 4; ++q) {
      unsigned xs[4] = {pk[q].x, pk[q].y, pk[q].z, pk[q].w};
#pragma unroll
      for (int h = 0; h < 4; ++h) {
        ud[q][2 * h] = bf2f_lo(xs[h]);
        ud[q][2 * h + 1] = bf2f_hi(xs[h]);
      }
      float p = 0.f;
#pragma unroll
      for (int j = 0; j < 8; ++j) p = fmaf(ud[q][j], v[q][j], p);
      p += __shfl_xor(p, 1);  // reduce over the 4-lane group (same o)
      p += __shfl_xor(p, 2);
      d[q] = p;
    }
    float bno[4];
    if (add_b1) {
#pragma unroll
      for (int q = 0; q < 4; ++q) bno[q] = d[q] + b1v[q];
    } else {
#pragma unroll
      for (int q = 0; q < 4; ++q) bno[q] = d[q];
      if ((lane & 3) == 0) {
#pragma unroll
        for (int q = 0; q < 4; ++q) b1[bbase + 16 * q] = d[q];
      }
    }
    // softmax over all 64 o: lanes with same (lane&3) jointly cover every o
    // exactly once, so xor levels 4..32 give the true sum.
    float m = fmaxf(fmaxf(bno[0], bno[1]), fmaxf(bno[2], bno[3]));
#pragma unroll
    for (int dl = 4; dl < 64; dl <<= 1) m = fmaxf(m, __shfl_xor(m, dl));
    float e0 = __expf(bno[0] - m);
    float e1 = __expf(bno[1] - m);
    float e2 = __expf(bno[2] - m);
    float e3 = __expf(bno[3] - m);
    float ls = (e0 + e1) + (e2 + e3);
#pragma unroll
    for (int dl = 4; dl < 64; dl <<= 1) ls += __shfl_xor(ls, dl);
    float inv = 1.0f / ls;
    float c[4] = {e0 * inv, e1 * inv, e2 * inv, e3 * inv};
#pragma unroll
    for (int q = 0; q < 4; ++q) {
#pragma unroll
      for (int j = 0; j < 8; ++j)
        racc[q][j] = fmaf(c[q], ud[q][j], racc[q][j]);
    }
  };

#pragma unroll
  for (int kk = 0; kk < 4; ++kk) {
    {
#pragma unroll
      for (int q = 0; q < 4; ++q)
        pB[q] = *(const uint4*)(ub + (size_t)(2 * kk + 1) * OLSZ + q * 512);
    }
    process(pA, 2 * kk);
    if (2 * kk + 2 < 8) {
#pragma unroll
      for (int q = 0; q < 4; ++q)
        pA[q] = *(const uint4*)(ub + (size_t)(2 * kk + 2) * OLSZ + q * 512);
    }
    process(pB, 2 * kk + 1);
  }

  // cross-wave reduction in LDS, then one atomicAdd per element per block
#pragma unroll
  for (int q = 0; q < 4; ++q) {
    float* dst = &red[wave][q * 512 + lane * 8];
    *(float4*)(dst) =
        make_float4(racc[q][0], racc[q][1], racc[q][2], racc[q][3]);
    *(float4*)(dst + 4) =
        make_float4(racc[q][4], racc[q][5], racc[q][6], racc[q][7]);
  }
  __syncthreads();
  float* so = sout + (size_t)b * OLSZ;
#pragma unroll
  for (int j = 0; j < 8; ++j) {
    const int idx = t + 256 * j;  // conflict-free strided read
    float s = (red[0][idx] + red[1][idx]) + (red[2][idx] + red[3][idx]);
    atomicAdd(so + idx, s);
  }
}

// K5: out = squash(s3)
__global__ __launch_bounds__(256) void k_final(const float* __restrict__ s3,
                                               float* __restrict__ out) {
  const int b = blockIdx.x;
  const int t = threadIdx.x;
  __shared__ float norm2[64];
  if (t < 64) norm2[t] = 0.f;
  __syncthreads();
  float scv[8];
#pragma unroll
  for (int k = 0; k < 8; ++k) {
    int idx = t + k * 256;
    float sc = s3[b * OLSZ + idx];
    scv[k] = sc;
    atomicAdd(&norm2[idx >> 5], sc * sc);
  }
  __syncthreads();
#pragma unroll
  for (int k = 0; k < 8; ++k) {
    int idx = t + k * 256;
    int o = idx >> 5;
    float n2 = norm2[o];
    float f = n2 / ((1.f + n2) * (sqrtf(n2) + 1e-5f));
    out[b * OLSZ + idx] = scv[k] * f;
  }
}

extern "C" void kernel_launch(void* const* d_in, const int* in_sizes, int n_in,
                              void* d_out, int out_size, void* d_ws,
                              size_t ws_size, hipStream_t stream) {
  const float* u = (const float*)d_in[0];
  const float* w = (const float*)d_in[1];
  const float* bias = (const float*)d_in[2];
  float* out = (float*)d_out;

  char* ws = (char*)d_ws;
  unsigned short* uhat = (unsigned short*)ws;                 // 268435456 B
  float* b1 = (float*)(ws + (size_t)268435456);               // 16777216 B
  float* s1 = (float*)(ws + (size_t)268435456 + 16777216);    // 524288 B
  float* s2 = s1 + 131072;                                    // 524288 B
  float* s3 = s2 + 131072;                                    // 524288 B

  hipMemsetAsync(s1, 0, 3 * 131072 * sizeof(float), stream);

  k_gemm<<<dim3(1024), dim3(256), 0, stream>>>(u, w, bias, uhat);
  k_sum_n<<<dim3(2048), dim3(256), 0, stream>>>(uhat, s1);
  k_route<<<dim3(2048), dim3(256), 0, stream>>>(uhat, s1, 1.0f / 64.0f, b1, 0, s2);
  k_route<<<dim3(2048), dim3(256), 0, stream>>>(uhat, s2, 1.0f, b1, 1, s3);
  k_final<<<dim3(64), dim3(256), 0, stream>>>(s3, out);
}